// Round 9
// baseline (222.435 us; speedup 1.0000x reference)
//
#include <hip/hip_runtime.h>

#define EMBED 1024
#define NH 16
#define HD 64
#define SEQ 2048
#define BATCH 2
#define ROWS (BATCH*SEQ)   // 4096
#define BHD (BATCH*NH)     // 32

typedef __bf16 bf16x8 __attribute__((ext_vector_type(8)));
typedef _Float16 f16x4 __attribute__((ext_vector_type(4)));
typedef float f32x4 __attribute__((ext_vector_type(4)));

__device__ __forceinline__ unsigned short f2bf(float f){
  union { float f; unsigned u; } v; v.f = f;
  unsigned r = v.u + 0x7fffu + ((v.u >> 16) & 1u);
  return (unsigned short)(r >> 16);
}
__device__ __forceinline__ float bf2f(unsigned short s){
  union { unsigned u; float f; } v; v.u = ((unsigned)s) << 16; return v.f;
}
__device__ __forceinline__ unsigned short f2h(float f){
  union { _Float16 h; unsigned short u; } v; v.h = (_Float16)f; return v.u;
}

// async global->LDS, 16B per lane; lds ptr must be wave-uniform base (lane*16 implicit)
typedef __attribute__((address_space(1))) unsigned int as1_t;
typedef __attribute__((address_space(3))) unsigned int as3_t;
__device__ __forceinline__ void async_ld16(const void* gp, void* lp){
  __builtin_amdgcn_global_load_lds((as1_t*)gp, (as3_t*)lp, 16, 0, 0);
}

// ---------------- merged prep: x->bf16 conv | w_qkv^T | w_out^T ----------------

__global__ __launch_bounds__(256) void k_prep(
    const float* __restrict__ x,     unsigned short* __restrict__ xb,
    const float* __restrict__ wqkv,  unsigned short* __restrict__ wqkvT,
    const float* __restrict__ wout,  unsigned short* __restrict__ woutT)
{
  __shared__ float t[32][33];
  int tid = threadIdx.x;
  int bx = blockIdx.x;
  if (bx < 4096){                      // conv: 1M float4
    int i = bx*256 + tid;
    float4 f = ((const float4*)x)[i];
    ushort4 o; o.x=f2bf(f.x); o.y=f2bf(f.y); o.z=f2bf(f.z); o.w=f2bf(f.w);
    ((ushort4*)xb)[i] = o;
    return;
  }
  const float* in; unsigned short* out; int R, C, c0, r0;
  if (bx < 4096 + 3072){               // w_qkv [1024][3072] -> [3072][1024]
    int bid = bx - 4096;
    in = wqkv; out = wqkvT; R = 1024; C = 3072;
    c0 = (bid % 96) * 32; r0 = (bid / 96) * 32;
  } else {                             // w_out [1024][1024] -> [1024][1024]^T
    int bid = bx - 7168;
    in = wout; out = woutT; R = 1024; C = 1024;
    c0 = (bid & 31) * 32; r0 = (bid >> 5) * 32;
  }
  int tx = tid & 31, ty = tid >> 5;
  #pragma unroll
  for (int i = 0; i < 4; i++){ int r = ty + i*8; t[r][tx] = in[(size_t)(r0+r)*C + c0 + tx]; }
  __syncthreads();
  #pragma unroll
  for (int i = 0; i < 4; i++){ int rr = ty + i*8; out[(size_t)(c0+rr)*R + r0 + tx] = f2bf(t[tx][rr]); }
}

// ---------------- GEMM1: 128x128 tile, global_load_lds staging ----------------
// Epilogue fusions: q/k -> bf16 [BH][L][D] + per-row norms (of ROUNDED values);
//                   v -> f16 V^T [BH][D][SEQ] directly (8B packed stores).

__global__ __launch_bounds__(256) void k_gemm_qkv(
    const unsigned short* __restrict__ A,    // [4096][1024] bf16
    const unsigned short* __restrict__ BT,   // [3072][1024] bf16
    const float* __restrict__ bias,          // [3072]
    unsigned short* __restrict__ qo, unsigned short* __restrict__ ko,
    unsigned short* __restrict__ vT,         // f16 bits [BH][D][SEQ]
    float* __restrict__ qn, float* __restrict__ kn)
{
  __shared__ __align__(16) unsigned short As[128*32];
  __shared__ __align__(16) unsigned short Bs[128*32];
  const int K = EMBED;
  int m0 = blockIdx.x * 128, n0 = blockIdx.y * 128;
  int tid = threadIdx.x, lane = tid & 63, wave = tid >> 6;
  int wm = wave >> 1, wn = wave & 1;
  int l16 = lane & 15, quad = lane >> 4;
  f32x4 acc[4][4] = {};
  int c0i = wave*64 + lane, c1i = 256 + wave*64 + lane;
  int r0 = c0i >> 2, cc0 = (c0i & 3) * 8;
  int r1 = c1i >> 2, cc1 = (c1i & 3) * 8;
  unsigned short* lA0 = &As[(wave*64)*8];
  unsigned short* lA1 = &As[(256 + wave*64)*8];
  unsigned short* lB0 = &Bs[(wave*64)*8];
  unsigned short* lB1 = &Bs[(256 + wave*64)*8];
  for (int k0 = 0; k0 < K; k0 += 32){
    async_ld16((void*)&A [(size_t)(m0 + r0)*K + k0 + cc0], (void*)lA0);
    async_ld16((void*)&A [(size_t)(m0 + r1)*K + k0 + cc1], (void*)lA1);
    async_ld16((void*)&BT[(size_t)(n0 + r0)*K + k0 + cc0], (void*)lB0);
    async_ld16((void*)&BT[(size_t)(n0 + r1)*K + k0 + cc1], (void*)lB1);
    __syncthreads();
    bf16x8 af[4], bfr[4];
    #pragma unroll
    for (int mi = 0; mi < 4; mi++) af[mi]  = *(const bf16x8*)&As[(wm*64 + mi*16 + l16)*32 + quad*8];
    #pragma unroll
    for (int ni = 0; ni < 4; ni++) bfr[ni] = *(const bf16x8*)&Bs[(wn*64 + ni*16 + l16)*32 + quad*8];
    #pragma unroll
    for (int mi = 0; mi < 4; mi++)
      #pragma unroll
      for (int ni = 0; ni < 4; ni++)
        acc[mi][ni] = __builtin_amdgcn_mfma_f32_16x16x32_bf16(af[mi], bfr[ni], acc[mi][ni], 0, 0, 0);
    __syncthreads();
  }

  int which = n0 >> 10;                // 0=q 1=k 2=v (uniform per block: 1024%128==0)
  int h = ((n0 & 1023) >> 6) + wn;     // head (uniform per wave: wave spans one head)
  if (which < 2){
    unsigned short* dst = (which == 0) ? qo : ko;
    float* ndst = (which == 0) ? qn : kn;
    #pragma unroll
    for (int mi = 0; mi < 4; mi++){
      float ns[4] = {0.f, 0.f, 0.f, 0.f};
      #pragma unroll
      for (int ni = 0; ni < 4; ni++)
        #pragma unroll
        for (int rr = 0; rr < 4; rr++){
          int row = m0 + wm*64 + mi*16 + quad*4 + rr;
          int col = n0 + wn*64 + ni*16 + l16;
          unsigned short bits = f2bf(acc[mi][ni][rr] + bias[col]);
          int b = row >> 11, l = row & 2047;
          dst[(((size_t)(b*NH + h))*SEQ + l)*HD + (col & 63)] = bits;
          float vq = bf2f(bits);
          ns[rr] += vq * vq;           // norm of the ROUNDED value (den >= 0)
        }
      #pragma unroll
      for (int rr = 0; rr < 4; rr++){  // reduce over the 16 l16 lanes (one head = 64 d)
        float s = ns[rr];
        s += __shfl_xor(s, 1); s += __shfl_xor(s, 2);
        s += __shfl_xor(s, 4); s += __shfl_xor(s, 8);
        if (l16 == 0){
          int row = m0 + wm*64 + mi*16 + quad*4 + rr;
          int b = row >> 11, l = row & 2047;
          ndst[(size_t)(b*NH + h)*SEQ + l] = s;
        }
      }
    }
  } else {
    #pragma unroll
    for (int mi = 0; mi < 4; mi++)
      #pragma unroll
      for (int ni = 0; ni < 4; ni++){
        int row0 = m0 + wm*64 + mi*16 + quad*4;      // 4 consecutive l (rr)
        int col = n0 + wn*64 + ni*16 + l16;
        int b = row0 >> 11, l0 = row0 & 2047;
        ushort4 pk; unsigned short* pks = (unsigned short*)&pk;
        #pragma unroll
        for (int rr = 0; rr < 4; rr++)
          pks[rr] = f2h(acc[mi][ni][rr] + bias[col]);
        *(ushort4*)&vT[(((size_t)(b*NH + h))*HD + (col & 63))*SEQ + l0] = pk;
      }
  }
}

// ---------------- attention: block (P,s) = j-segment s of tile pair {P, 63-P} ----------------
// (unchanged from R8)

__global__ __launch_bounds__(128, 4) void k_attn(
    const unsigned short* __restrict__ qg,   // [BH][L][D] bf16
    const unsigned short* __restrict__ kg,   // [BH][L][D] bf16
    const unsigned short* __restrict__ vtg,  // [BH][D][L] f16
    const float* __restrict__ qn,
    const float* __restrict__ kn,
    float* __restrict__ Opart,               // [BH*64 tiles][2 segs][32 r][64 d] f32
    float* __restrict__ Mp,                  // [BH*64][2][32]
    float* __restrict__ Lp)                  // [BH*64][2][32]
{
  __shared__ __align__(16) unsigned short Ks[2][32*72];  // 2 x 4.5 KB
  __shared__ __align__(16) _Float16      Vs[2][64*36];   // 2 x 4.5 KB
  int bh = blockIdx.y;
  int tid = threadIdx.x, lane = tid & 63, wave = tid >> 6;   // wave 0..1
  int l16 = lane & 15, quad = lane >> 4;
  int P = blockIdx.x >> 1, s = blockIdx.x & 1;   // pair 0..31, segment 0..1

  const unsigned short* qbase = qg  + (size_t)bh * SEQ * HD;
  const unsigned short* kbase = kg  + (size_t)bh * SEQ * HD;
  const _Float16*       vtb   = (const _Float16*)vtg + (size_t)bh * HD * SEQ;
  const float* knb = kn + (size_t)bh * SEQ;

  int kd0 = tid >> 3,         kc0 = tid & 7;     // K rows 0..15
  int kd1 = (tid + 128) >> 3, kc1 = tid & 7;     // K rows 16..31
  int vd0 = tid >> 2,         vc0 = tid & 3;     // V rows 0..31
  int vd1 = 32 + (tid >> 2),  vc1 = tid & 3;     // V rows 32..63

  #pragma unroll
  for (int pass = 0; pass < 2; pass++){
    int t = pass ? (63 - P) : P;
    int nj = t + 1;
    int half = (nj + 1) >> 1;
    int jb_lo = s ? half : 0;
    int jb_hi = s ? nj : half;
    int q0 = t*32 + wave*16;

    bf16x8 aq[2];
    #pragma unroll
    for (int sk = 0; sk < 2; sk++)
      aq[sk] = *(const bf16x8*)&qbase[(size_t)(q0 + l16)*HD + sk*32 + quad*8];
    float qn_m = qn[(size_t)bh*SEQ + q0 + l16];

    float m_run = -1e30f, l_lane = 0.f;
    f32x4 oacc[4] = {};

    if (jb_lo < jb_hi){
      int jlo = jb_lo * 32;
      {
        uint4 ka = *(const uint4*)&kbase[(size_t)(jlo + kd0)*HD + kc0*8];
        uint4 kb = *(const uint4*)&kbase[(size_t)(jlo + kd1)*HD + kc1*8];
        uint4 va = *(const uint4*)&vtb[(size_t)vd0*SEQ + jlo + vc0*8];
        uint4 vb = *(const uint4*)&vtb[(size_t)vd1*SEQ + jlo + vc1*8];
        *(uint4*)&Ks[0][kd0*72 + kc0*8] = ka;
        *(uint4*)&Ks[0][kd1*72 + kc1*8] = kb;
        *(uint2*)&Vs[0][vd0*36 + vc0*8]     = make_uint2(va.x, va.y);
        *(uint2*)&Vs[0][vd0*36 + vc0*8 + 4] = make_uint2(va.z, va.w);
        *(uint2*)&Vs[0][vd1*36 + vc1*8]     = make_uint2(vb.x, vb.y);
        *(uint2*)&Vs[0][vd1*36 + vc1*8 + 4] = make_uint2(vb.z, vb.w);
      }
      __syncthreads();

      for (int jb = jb_lo; jb < jb_hi; jb++){
        int j0 = jb * 32;
        int buf = (jb - jb_lo) & 1;
        int jn = (jb + 1 < jb_hi) ? (jb + 1)*32 : j0;
        uint4 ka = *(const uint4*)&kbase[(size_t)(jn + kd0)*HD + kc0*8];
        uint4 kb = *(const uint4*)&kbase[(size_t)(jn + kd1)*HD + kc1*8];
        uint4 va = *(const uint4*)&vtb[(size_t)vd0*SEQ + jn + vc0*8];
        uint4 vb = *(const uint4*)&vtb[(size_t)vd1*SEQ + jn + vc1*8];

        f32x4 st[2] = {};
        #pragma unroll
        for (int tile = 0; tile < 2; tile++)
          #pragma unroll
          for (int sk = 0; sk < 2; sk++){
            bf16x8 ak = *(const bf16x8*)&Ks[buf][(tile*16 + l16)*72 + (sk*4 + quad)*8];
            st[tile] = __builtin_amdgcn_mfma_f32_16x16x32_bf16(ak, aq[sk], st[tile], 0, 0, 0);
          }
        float4 kn_a = *(const float4*)&knb[j0 + quad*4];
        float4 kn_b = *(const float4*)&knb[j0 + 16 + quad*4];
        float kn_j[2][4] = {{kn_a.x, kn_a.y, kn_a.z, kn_a.w}, {kn_b.x, kn_b.y, kn_b.z, kn_b.w}};
        int mg = q0 + l16;
        float sc[2][4];
        if (j0 + 32 > q0){
          #pragma unroll
          for (int tile = 0; tile < 2; tile++)
            #pragma unroll
            for (int rr = 0; rr < 4; rr++){
              int jg = j0 + tile*16 + quad*4 + rr;
              float dot = st[tile][rr];
              float den = fmaxf(qn_m + kn_j[tile][rr] - 2.0f*dot, 0.0f) + 1e-6f;
              float v = dot * dot * __builtin_amdgcn_rcpf(den);
              sc[tile][rr] = (jg <= mg) ? v : -1e30f;
            }
        } else {
          #pragma unroll
          for (int tile = 0; tile < 2; tile++)
            #pragma unroll
            for (int rr = 0; rr < 4; rr++){
              float dot = st[tile][rr];
              float den = fmaxf(qn_m + kn_j[tile][rr] - 2.0f*dot, 0.0f) + 1e-6f;
              sc[tile][rr] = dot * dot * __builtin_amdgcn_rcpf(den);
            }
        }
        float mx = fmaxf(fmaxf(fmaxf(sc[0][0], sc[0][1]), fmaxf(sc[0][2], sc[0][3])),
                         fmaxf(fmaxf(sc[1][0], sc[1][1]), fmaxf(sc[1][2], sc[1][3])));
        mx = fmaxf(mx, __shfl_xor(mx, 16));
        mx = fmaxf(mx, __shfl_xor(mx, 32));
        float mnew = fmaxf(m_run, mx);
        float alpha = __expf(m_run - mnew);
        m_run = mnew;

        float ps = 0.f;
        #pragma unroll
        for (int tile = 0; tile < 2; tile++)
          #pragma unroll
          for (int rr = 0; rr < 4; rr++){
            float e = __expf(sc[tile][rr] - mnew);
            sc[tile][rr] = e; ps += e;
          }
        l_lane = l_lane * alpha + ps;

        #pragma unroll
        for (int g = 0; g < 4; g++)
          #pragma unroll
          for (int rr = 0; rr < 4; rr++) oacc[g][rr] *= alpha;

        #pragma unroll
        for (int tile = 0; tile < 2; tile++){
          f16x4 pf;
          #pragma unroll
          for (int rr = 0; rr < 4; rr++) pf[rr] = (_Float16)sc[tile][rr];
          #pragma unroll
          for (int g = 0; g < 4; g++){
            f16x4 av = *(const f16x4*)&Vs[buf][(g*16 + l16)*36 + (tile*4 + quad)*4];
            oacc[g] = __builtin_amdgcn_mfma_f32_16x16x16f16(av, pf, oacc[g], 0, 0, 0);
          }
        }

        *(uint4*)&Ks[buf^1][kd0*72 + kc0*8] = ka;
        *(uint4*)&Ks[buf^1][kd1*72 + kc1*8] = kb;
        *(uint2*)&Vs[buf^1][vd0*36 + vc0*8]     = make_uint2(va.x, va.y);
        *(uint2*)&Vs[buf^1][vd0*36 + vc0*8 + 4] = make_uint2(va.z, va.w);
        *(uint2*)&Vs[buf^1][vd1*36 + vc1*8]     = make_uint2(vb.x, vb.y);
        *(uint2*)&Vs[buf^1][vd1*36 + vc1*8 + 4] = make_uint2(vb.z, vb.w);
        __syncthreads();
      }
    }

    float l_tot = l_lane + __shfl_xor(l_lane, 16);
    l_tot += __shfl_xor(l_tot, 32);

    int r = wave*16 + l16;
    size_t pb = ((size_t)(bh*64 + t)*2 + s) * (32*64);
    #pragma unroll
    for (int g = 0; g < 4; g++){
      float4 pk = make_float4(oacc[g][0], oacc[g][1], oacc[g][2], oacc[g][3]);
      *(float4*)&Opart[pb + (size_t)r*64 + g*16 + quad*4] = pk;
    }
    if (quad == 0){
      int mb = ((bh*64 + t)*2 + s)*32 + r;
      Mp[mb] = m_run;
      Lp[mb] = l_tot;
    }
    __syncthreads();
  }
}

// ---------------- combine the 2 j-segments per tile ----------------

__global__ __launch_bounds__(256) void k_combine(
    const float* __restrict__ Opart,
    const float* __restrict__ Mp,
    const float* __restrict__ Lp,
    unsigned short* __restrict__ attn_out)
{
  int t = blockIdx.x;             // tile 0..63
  int bh = blockIdx.y; int b = bh >> 4, h = bh & 15;
  int tid = threadIdx.x;
  int d = tid & 63, r8 = (tid >> 6) * 8;
  size_t i0 = ((size_t)(bh*64 + t)*2) * 2048;
  size_t i1 = i0 + 2048;
  int mb = ((bh*64 + t)*2) * 32;
  #pragma unroll
  for (int rr = 0; rr < 8; rr++){
    int r = r8 + rr;
    float m0 = Mp[mb + r],      m1 = Mp[mb + 32 + r];
    float l0 = Lp[mb + r],      l1 = Lp[mb + 32 + r];
    float ms = fmaxf(m0, m1);
    float w0 = __expf(m0 - ms), w1 = __expf(m1 - ms);
    float den = w0*l0 + w1*l1;
    float o = (w0*Opart[i0 + (size_t)r*64 + d] + w1*Opart[i1 + (size_t)r*64 + d]) / den;
    attn_out[(size_t)(b*SEQ + t*32 + r)*EMBED + h*HD + d] = f2bf(o);
  }
}

// ---------------- GEMM2: 128x128 tile, attn_out @ w_out + b_out -> fp32 ----------------

__global__ __launch_bounds__(256) void k_gemm_out(
    const unsigned short* __restrict__ A,    // [4096][1024] bf16
    const unsigned short* __restrict__ BT,   // [1024][1024] bf16
    const float* __restrict__ bias,          // [1024]
    float* __restrict__ out)
{
  __shared__ __align__(16) unsigned short As[128*32];
  __shared__ __align__(16) unsigned short Bs[128*32];
  const int K = EMBED;
  int m0 = blockIdx.x * 128, n0 = blockIdx.y * 128;
  int tid = threadIdx.x, lane = tid & 63, wave = tid >> 6;
  int wm = wave >> 1, wn = wave & 1;
  int l16 = lane & 15, quad = lane >> 4;
  f32x4 acc[4][4] = {};
  int c0i = wave*64 + lane, c1i = 256 + wave*64 + lane;
  int r0 = c0i >> 2, cc0 = (c0i & 3) * 8;
  int r1 = c1i >> 2, cc1 = (c1i & 3) * 8;
  unsigned short* lA0 = &As[(wave*64)*8];
  unsigned short* lA1 = &As[(256 + wave*64)*8];
  unsigned short* lB0 = &Bs[(wave*64)*8];
  unsigned short* lB1 = &Bs[(256 + wave*64)*8];
  for (int k0 = 0; k0 < K; k0 += 32){
    async_ld16((void*)&A [(size_t)(m0 + r0)*K + k0 + cc0], (void*)lA0);
    async_ld16((void*)&A [(size_t)(m0 + r1)*K + k0 + cc1], (void*)lA1);
    async_ld16((void*)&BT[(size_t)(n0 + r0)*K + k0 + cc0], (void*)lB0);
    async_ld16((void*)&BT[(size_t)(n0 + r1)*K + k0 + cc1], (void*)lB1);
    __syncthreads();
    bf16x8 af[4], bfr[4];
    #pragma unroll
    for (int mi = 0; mi < 4; mi++) af[mi]  = *(const bf16x8*)&As[(wm*64 + mi*16 + l16)*32 + quad*8];
    #pragma unroll
    for (int ni = 0; ni < 4; ni++) bfr[ni] = *(const bf16x8*)&Bs[(wn*64 + ni*16 + l16)*32 + quad*8];
    #pragma unroll
    for (int mi = 0; mi < 4; mi++)
      #pragma unroll
      for (int ni = 0; ni < 4; ni++)
        acc[mi][ni] = __builtin_amdgcn_mfma_f32_16x16x32_bf16(af[mi], bfr[ni], acc[mi][ni], 0, 0, 0);
    __syncthreads();
  }
  #pragma unroll
  for (int mi = 0; mi < 4; mi++)
    #pragma unroll
    for (int ni = 0; ni < 4; ni++)
      #pragma unroll
      for (int rr = 0; rr < 4; rr++){
        int row = m0 + wm*64 + mi*16 + quad*4 + rr;
        int col = n0 + wn*64 + ni*16 + l16;
        out[(size_t)row*EMBED + col] = acc[mi][ni][rr] + bias[col];
      }
}

// ---------------- launch ----------------

extern "C" void kernel_launch(void* const* d_in, const int* in_sizes, int n_in,
                              void* d_out, int out_size, void* d_ws, size_t ws_size,
                              hipStream_t stream) {
  const float* x     = (const float*)d_in[0];
  const float* w_qkv = (const float*)d_in[1];
  const float* b_qkv = (const float*)d_in[2];
  const float* w_out = (const float*)d_in[3];
  const float* b_out = (const float*)d_in[4];
  float* out = (float*)d_out;

  char* ws = (char*)d_ws;
  size_t off = 0;
  auto alloc = [&](size_t bytes) -> void* {
    void* p = ws + off; off += (bytes + 255) & ~(size_t)255; return p;
  };
  unsigned short* xb    = (unsigned short*)alloc((size_t)ROWS * EMBED * 2);      // 8 MB
  unsigned short* wqkvT = (unsigned short*)alloc((size_t)3 * EMBED * EMBED * 2); // 6 MB
  unsigned short* woutT = (unsigned short*)alloc((size_t)EMBED * EMBED * 2);     // 2 MB
  unsigned short* qb    = (unsigned short*)alloc((size_t)ROWS * EMBED * 2);
  unsigned short* kb    = (unsigned short*)alloc((size_t)ROWS * EMBED * 2);
  unsigned short* vTb   = (unsigned short*)alloc((size_t)ROWS * EMBED * 2);      // f16 bits [BH][D][SEQ]
  float* qn = (float*)alloc((size_t)BHD * SEQ * 4);
  float* kn = (float*)alloc((size_t)BHD * SEQ * 4);
  float* Opart = (float*)alloc((size_t)BHD * 64 * 2 * 32 * 64 * 4);              // 33.5 MB
  float* Mp    = (float*)alloc((size_t)BHD * 64 * 2 * 32 * 4);                   // 0.5 MB
  float* Lp    = (float*)alloc((size_t)BHD * 64 * 2 * 32 * 4);                   // 0.5 MB
  unsigned short* attnb = xb;  // xb dead after GEMM1 — alias

  k_prep<<<dim3(4096 + 3072 + 1024), dim3(256), 0, stream>>>(x, xb, w_qkv, wqkvT, w_out, woutT);
  k_gemm_qkv<<<dim3(ROWS/128, 3*EMBED/128), dim3(256), 0, stream>>>(xb, wqkvT, b_qkv, qb, kb, vTb, qn, kn);
  k_attn<<<dim3(64, BHD), dim3(128), 0, stream>>>(qb, kb, vTb, qn, kn, Opart, Mp, Lp);
  k_combine<<<dim3(64, BHD), dim3(256), 0, stream>>>(Opart, Mp, Lp, attnb);
  k_gemm_out<<<dim3(ROWS/128, EMBED/128), dim3(256), 0, stream>>>(attnb, woutT, b_out, out);
}

// Round 10
// 218.794 us; speedup vs baseline: 1.0166x; 1.0166x over previous
//
#include <hip/hip_runtime.h>

#define EMBED 1024
#define NH 16
#define HD 64
#define SEQ 2048
#define BATCH 2
#define ROWS (BATCH*SEQ)   // 4096
#define BHD (BATCH*NH)     // 32

typedef __bf16 bf16x8 __attribute__((ext_vector_type(8)));
typedef _Float16 f16x4 __attribute__((ext_vector_type(4)));
typedef float f32x4 __attribute__((ext_vector_type(4)));

__device__ __forceinline__ unsigned short f2bf(float f){
  union { float f; unsigned u; } v; v.f = f;
  unsigned r = v.u + 0x7fffu + ((v.u >> 16) & 1u);
  return (unsigned short)(r >> 16);
}
__device__ __forceinline__ float bf2f(unsigned short s){
  union { unsigned u; float f; } v; v.u = ((unsigned)s) << 16; return v.f;
}
__device__ __forceinline__ unsigned short f2h(float f){
  union { _Float16 h; unsigned short u; } v; v.h = (_Float16)f; return v.u;
}

// async global->LDS, 16B per lane; lds ptr must be wave-uniform base (lane*16 implicit)
typedef __attribute__((address_space(1))) unsigned int as1_t;
typedef __attribute__((address_space(3))) unsigned int as3_t;
__device__ __forceinline__ void async_ld16(const void* gp, void* lp){
  __builtin_amdgcn_global_load_lds((as1_t*)gp, (as3_t*)lp, 16, 0, 0);
}

// ---------------- merged prep: x->bf16 conv | w_qkv^T | w_out^T ----------------

__global__ __launch_bounds__(256) void k_prep(
    const float* __restrict__ x,     unsigned short* __restrict__ xb,
    const float* __restrict__ wqkv,  unsigned short* __restrict__ wqkvT,
    const float* __restrict__ wout,  unsigned short* __restrict__ woutT)
{
  __shared__ float t[32][33];
  int tid = threadIdx.x;
  int bx = blockIdx.x;
  if (bx < 4096){                      // conv: 1M float4
    int i = bx*256 + tid;
    float4 f = ((const float4*)x)[i];
    ushort4 o; o.x=f2bf(f.x); o.y=f2bf(f.y); o.z=f2bf(f.z); o.w=f2bf(f.w);
    ((ushort4*)xb)[i] = o;
    return;
  }
  const float* in; unsigned short* out; int R, C, c0, r0;
  if (bx < 4096 + 3072){               // w_qkv [1024][3072] -> [3072][1024]
    int bid = bx - 4096;
    in = wqkv; out = wqkvT; R = 1024; C = 3072;
    c0 = (bid % 96) * 32; r0 = (bid / 96) * 32;
  } else {                             // w_out [1024][1024] -> transpose
    int bid = bx - 7168;
    in = wout; out = woutT; R = 1024; C = 1024;
    c0 = (bid & 31) * 32; r0 = (bid >> 5) * 32;
  }
  int tx = tid & 31, ty = tid >> 5;
  #pragma unroll
  for (int i = 0; i < 4; i++){ int r = ty + i*8; t[r][tx] = in[(size_t)(r0+r)*C + c0 + tx]; }
  __syncthreads();
  #pragma unroll
  for (int i = 0; i < 4; i++){ int rr = ty + i*8; out[(size_t)(c0+rr)*R + r0 + tx] = f2bf(t[tx][rr]); }
}

// ---------------- GEMM1: 128x128 tile, global_load_lds staging ----------------
// Epilogue: q -> bf16 [BH][L][D] (plain stores; qn computed in k_attn);
//           k -> bf16 [BH][L][D] + kn of ROUNDED values;
//           v -> f16 V^T [BH][D][SEQ] (8B packed stores).

__global__ __launch_bounds__(256) void k_gemm_qkv(
    const unsigned short* __restrict__ A,    // [4096][1024] bf16
    const unsigned short* __restrict__ BT,   // [3072][1024] bf16
    const float* __restrict__ bias,          // [3072]
    unsigned short* __restrict__ qo, unsigned short* __restrict__ ko,
    unsigned short* __restrict__ vT,         // f16 bits [BH][D][SEQ]
    float* __restrict__ kn)
{
  __shared__ __align__(16) unsigned short As[128*32];
  __shared__ __align__(16) unsigned short Bs[128*32];
  const int K = EMBED;
  int m0 = blockIdx.x * 128, n0 = blockIdx.y * 128;
  int tid = threadIdx.x, lane = tid & 63, wave = tid >> 6;
  int wm = wave >> 1, wn = wave & 1;
  int l16 = lane & 15, quad = lane >> 4;
  f32x4 acc[4][4] = {};
  int c0i = wave*64 + lane, c1i = 256 + wave*64 + lane;
  int r0 = c0i >> 2, cc0 = (c0i & 3) * 8;
  int r1 = c1i >> 2, cc1 = (c1i & 3) * 8;
  unsigned short* lA0 = &As[(wave*64)*8];
  unsigned short* lA1 = &As[(256 + wave*64)*8];
  unsigned short* lB0 = &Bs[(wave*64)*8];
  unsigned short* lB1 = &Bs[(256 + wave*64)*8];
  for (int k0 = 0; k0 < K; k0 += 32){
    async_ld16((void*)&A [(size_t)(m0 + r0)*K + k0 + cc0], (void*)lA0);
    async_ld16((void*)&A [(size_t)(m0 + r1)*K + k0 + cc1], (void*)lA1);
    async_ld16((void*)&BT[(size_t)(n0 + r0)*K + k0 + cc0], (void*)lB0);
    async_ld16((void*)&BT[(size_t)(n0 + r1)*K + k0 + cc1], (void*)lB1);
    __syncthreads();
    bf16x8 af[4], bfr[4];
    #pragma unroll
    for (int mi = 0; mi < 4; mi++) af[mi]  = *(const bf16x8*)&As[(wm*64 + mi*16 + l16)*32 + quad*8];
    #pragma unroll
    for (int ni = 0; ni < 4; ni++) bfr[ni] = *(const bf16x8*)&Bs[(wn*64 + ni*16 + l16)*32 + quad*8];
    #pragma unroll
    for (int mi = 0; mi < 4; mi++)
      #pragma unroll
      for (int ni = 0; ni < 4; ni++)
        acc[mi][ni] = __builtin_amdgcn_mfma_f32_16x16x32_bf16(af[mi], bfr[ni], acc[mi][ni], 0, 0, 0);
    __syncthreads();
  }

  int which = n0 >> 10;                // 0=q 1=k 2=v (uniform per block)
  int h = ((n0 & 1023) >> 6) + wn;     // head (uniform per wave)
  if (which == 0){
    #pragma unroll
    for (int mi = 0; mi < 4; mi++)
      #pragma unroll
      for (int ni = 0; ni < 4; ni++)
        #pragma unroll
        for (int rr = 0; rr < 4; rr++){
          int row = m0 + wm*64 + mi*16 + quad*4 + rr;
          int col = n0 + wn*64 + ni*16 + l16;
          int b = row >> 11, l = row & 2047;
          qo[(((size_t)(b*NH + h))*SEQ + l)*HD + (col & 63)] = f2bf(acc[mi][ni][rr] + bias[col]);
        }
  } else if (which == 1){
    #pragma unroll
    for (int mi = 0; mi < 4; mi++){
      float ns[4] = {0.f, 0.f, 0.f, 0.f};
      #pragma unroll
      for (int ni = 0; ni < 4; ni++)
        #pragma unroll
        for (int rr = 0; rr < 4; rr++){
          int row = m0 + wm*64 + mi*16 + quad*4 + rr;
          int col = n0 + wn*64 + ni*16 + l16;
          unsigned short bits = f2bf(acc[mi][ni][rr] + bias[col]);
          int b = row >> 11, l = row & 2047;
          ko[(((size_t)(b*NH + h))*SEQ + l)*HD + (col & 63)] = bits;
          float vq = bf2f(bits);
          ns[rr] += vq * vq;           // norm of the ROUNDED value (den >= 0)
        }
      #pragma unroll
      for (int rr = 0; rr < 4; rr++){  // reduce over the 16 l16 lanes (one head = 64 d)
        float s = ns[rr];
        s += __shfl_xor(s, 1); s += __shfl_xor(s, 2);
        s += __shfl_xor(s, 4); s += __shfl_xor(s, 8);
        if (l16 == 0){
          int row = m0 + wm*64 + mi*16 + quad*4 + rr;
          int b = row >> 11, l = row & 2047;
          kn[(size_t)(b*NH + h)*SEQ + l] = s;
        }
      }
    }
  } else {
    #pragma unroll
    for (int mi = 0; mi < 4; mi++)
      #pragma unroll
      for (int ni = 0; ni < 4; ni++){
        int row0 = m0 + wm*64 + mi*16 + quad*4;      // 4 consecutive l (rr)
        int col = n0 + wn*64 + ni*16 + l16;
        int b = row0 >> 11, l0 = row0 & 2047;
        ushort4 pk; unsigned short* pks = (unsigned short*)&pk;
        #pragma unroll
        for (int rr = 0; rr < 4; rr++)
          pks[rr] = f2h(acc[mi][ni][rr] + bias[col]);
        *(ushort4*)&vT[(((size_t)(b*NH + h))*HD + (col & 63))*SEQ + l0] = pk;
      }
  }
}

// ---------------- attention: block (P,s) = j-segment s of tile pair {P, 63-P} ----------------
// R8 structure; qn computed in-kernel from rounded aq frags; Opart now f16.

__global__ __launch_bounds__(128, 4) void k_attn(
    const unsigned short* __restrict__ qg,   // [BH][L][D] bf16
    const unsigned short* __restrict__ kg,   // [BH][L][D] bf16
    const unsigned short* __restrict__ vtg,  // [BH][D][L] f16
    const float* __restrict__ kn,
    _Float16* __restrict__ Opart,            // [BH*64 tiles][2 segs][32 r][64 d] f16 (unnormalized)
    float* __restrict__ Mp,                  // [BH*64][2][32]
    float* __restrict__ Lp)                  // [BH*64][2][32]
{
  __shared__ __align__(16) unsigned short Ks[2][32*72];  // 2 x 4.5 KB
  __shared__ __align__(16) _Float16      Vs[2][64*36];   // 2 x 4.5 KB
  int bh = blockIdx.y;
  int tid = threadIdx.x, lane = tid & 63, wave = tid >> 6;   // wave 0..1
  int l16 = lane & 15, quad = lane >> 4;
  int P = blockIdx.x >> 1, s = blockIdx.x & 1;   // pair 0..31, segment 0..1

  const unsigned short* qbase = qg  + (size_t)bh * SEQ * HD;
  const unsigned short* kbase = kg  + (size_t)bh * SEQ * HD;
  const _Float16*       vtb   = (const _Float16*)vtg + (size_t)bh * HD * SEQ;
  const float* knb = kn + (size_t)bh * SEQ;

  int kd0 = tid >> 3,         kc0 = tid & 7;     // K rows 0..15
  int kd1 = (tid + 128) >> 3, kc1 = tid & 7;     // K rows 16..31
  int vd0 = tid >> 2,         vc0 = tid & 3;     // V rows 0..31
  int vd1 = 32 + (tid >> 2),  vc1 = tid & 3;     // V rows 32..63

  #pragma unroll
  for (int pass = 0; pass < 2; pass++){
    int t = pass ? (63 - P) : P;
    int nj = t + 1;
    int half = (nj + 1) >> 1;
    int jb_lo = s ? half : 0;
    int jb_hi = s ? nj : half;
    int q0 = t*32 + wave*16;

    bf16x8 aq[2];
    #pragma unroll
    for (int sk = 0; sk < 2; sk++)
      aq[sk] = *(const bf16x8*)&qbase[(size_t)(q0 + l16)*HD + sk*32 + quad*8];
    // qn of the ROUNDED q row (m = l16): lane-local 16 squares + cross-quad reduce
    float qn_lane = 0.f;
    #pragma unroll
    for (int sk = 0; sk < 2; sk++)
      #pragma unroll
      for (int i = 0; i < 8; i++){
        float v = (float)aq[sk][i];
        qn_lane += v * v;
      }
    float qn_m = qn_lane + __shfl_xor(qn_lane, 16);
    qn_m += __shfl_xor(qn_m, 32);

    float m_run = -1e30f, l_lane = 0.f;
    f32x4 oacc[4] = {};

    if (jb_lo < jb_hi){
      int jlo = jb_lo * 32;
      {
        uint4 ka = *(const uint4*)&kbase[(size_t)(jlo + kd0)*HD + kc0*8];
        uint4 kb = *(const uint4*)&kbase[(size_t)(jlo + kd1)*HD + kc1*8];
        uint4 va = *(const uint4*)&vtb[(size_t)vd0*SEQ + jlo + vc0*8];
        uint4 vb = *(const uint4*)&vtb[(size_t)vd1*SEQ + jlo + vc1*8];
        *(uint4*)&Ks[0][kd0*72 + kc0*8] = ka;
        *(uint4*)&Ks[0][kd1*72 + kc1*8] = kb;
        *(uint2*)&Vs[0][vd0*36 + vc0*8]     = make_uint2(va.x, va.y);
        *(uint2*)&Vs[0][vd0*36 + vc0*8 + 4] = make_uint2(va.z, va.w);
        *(uint2*)&Vs[0][vd1*36 + vc1*8]     = make_uint2(vb.x, vb.y);
        *(uint2*)&Vs[0][vd1*36 + vc1*8 + 4] = make_uint2(vb.z, vb.w);
      }
      __syncthreads();

      for (int jb = jb_lo; jb < jb_hi; jb++){
        int j0 = jb * 32;
        int buf = (jb - jb_lo) & 1;
        int jn = (jb + 1 < jb_hi) ? (jb + 1)*32 : j0;
        uint4 ka = *(const uint4*)&kbase[(size_t)(jn + kd0)*HD + kc0*8];
        uint4 kb = *(const uint4*)&kbase[(size_t)(jn + kd1)*HD + kc1*8];
        uint4 va = *(const uint4*)&vtb[(size_t)vd0*SEQ + jn + vc0*8];
        uint4 vb = *(const uint4*)&vtb[(size_t)vd1*SEQ + jn + vc1*8];

        f32x4 st[2] = {};
        #pragma unroll
        for (int tile = 0; tile < 2; tile++)
          #pragma unroll
          for (int sk = 0; sk < 2; sk++){
            bf16x8 ak = *(const bf16x8*)&Ks[buf][(tile*16 + l16)*72 + (sk*4 + quad)*8];
            st[tile] = __builtin_amdgcn_mfma_f32_16x16x32_bf16(ak, aq[sk], st[tile], 0, 0, 0);
          }
        float4 kn_a = *(const float4*)&knb[j0 + quad*4];
        float4 kn_b = *(const float4*)&knb[j0 + 16 + quad*4];
        float kn_j[2][4] = {{kn_a.x, kn_a.y, kn_a.z, kn_a.w}, {kn_b.x, kn_b.y, kn_b.z, kn_b.w}};
        int mg = q0 + l16;
        float sc[2][4];
        if (j0 + 32 > q0){
          #pragma unroll
          for (int tile = 0; tile < 2; tile++)
            #pragma unroll
            for (int rr = 0; rr < 4; rr++){
              int jg = j0 + tile*16 + quad*4 + rr;
              float dot = st[tile][rr];
              float den = fmaxf(qn_m + kn_j[tile][rr] - 2.0f*dot, 0.0f) + 1e-6f;
              float v = dot * dot * __builtin_amdgcn_rcpf(den);
              sc[tile][rr] = (jg <= mg) ? v : -1e30f;
            }
        } else {
          #pragma unroll
          for (int tile = 0; tile < 2; tile++)
            #pragma unroll
            for (int rr = 0; rr < 4; rr++){
              float dot = st[tile][rr];
              float den = fmaxf(qn_m + kn_j[tile][rr] - 2.0f*dot, 0.0f) + 1e-6f;
              sc[tile][rr] = dot * dot * __builtin_amdgcn_rcpf(den);
            }
        }
        float mx = fmaxf(fmaxf(fmaxf(sc[0][0], sc[0][1]), fmaxf(sc[0][2], sc[0][3])),
                         fmaxf(fmaxf(sc[1][0], sc[1][1]), fmaxf(sc[1][2], sc[1][3])));
        mx = fmaxf(mx, __shfl_xor(mx, 16));
        mx = fmaxf(mx, __shfl_xor(mx, 32));
        float mnew = fmaxf(m_run, mx);
        float alpha = __expf(m_run - mnew);
        m_run = mnew;

        float ps = 0.f;
        #pragma unroll
        for (int tile = 0; tile < 2; tile++)
          #pragma unroll
          for (int rr = 0; rr < 4; rr++){
            float e = __expf(sc[tile][rr] - mnew);
            sc[tile][rr] = e; ps += e;
          }
        l_lane = l_lane * alpha + ps;

        #pragma unroll
        for (int g = 0; g < 4; g++)
          #pragma unroll
          for (int rr = 0; rr < 4; rr++) oacc[g][rr] *= alpha;

        #pragma unroll
        for (int tile = 0; tile < 2; tile++){
          f16x4 pf;
          #pragma unroll
          for (int rr = 0; rr < 4; rr++) pf[rr] = (_Float16)sc[tile][rr];
          #pragma unroll
          for (int g = 0; g < 4; g++){
            f16x4 av = *(const f16x4*)&Vs[buf][(g*16 + l16)*36 + (tile*4 + quad)*4];
            oacc[g] = __builtin_amdgcn_mfma_f32_16x16x16f16(av, pf, oacc[g], 0, 0, 0);
          }
        }

        *(uint4*)&Ks[buf^1][kd0*72 + kc0*8] = ka;
        *(uint4*)&Ks[buf^1][kd1*72 + kc1*8] = kb;
        *(uint2*)&Vs[buf^1][vd0*36 + vc0*8]     = make_uint2(va.x, va.y);
        *(uint2*)&Vs[buf^1][vd0*36 + vc0*8 + 4] = make_uint2(va.z, va.w);
        *(uint2*)&Vs[buf^1][vd1*36 + vc1*8]     = make_uint2(vb.x, vb.y);
        *(uint2*)&Vs[buf^1][vd1*36 + vc1*8 + 4] = make_uint2(vb.z, vb.w);
        __syncthreads();
      }
    }

    float l_tot = l_lane + __shfl_xor(l_lane, 16);
    l_tot += __shfl_xor(l_tot, 32);

    // write UNNORMALIZED f16 partials: O^T regs (d = g*16+quad*4+rr, m = l16)
    int r = wave*16 + l16;
    size_t pb = ((size_t)(bh*64 + t)*2 + s) * (32*64);
    #pragma unroll
    for (int g = 0; g < 4; g++){
      ushort4 pk;
      pk.x = f2h(oacc[g][0]); pk.y = f2h(oacc[g][1]);
      pk.z = f2h(oacc[g][2]); pk.w = f2h(oacc[g][3]);
      *(ushort4*)&Opart[pb + (size_t)r*64 + g*16 + quad*4] = pk;
    }
    if (quad == 0){
      int mb = ((bh*64 + t)*2 + s)*32 + r;
      Mp[mb] = m_run;
      Lp[mb] = l_tot;
    }
    __syncthreads();
  }
}

// ---------------- combine the 2 j-segments per tile ----------------

__global__ __launch_bounds__(256) void k_combine(
    const _Float16* __restrict__ Opart,
    const float* __restrict__ Mp,
    const float* __restrict__ Lp,
    unsigned short* __restrict__ attn_out)
{
  int t = blockIdx.x;             // tile 0..63
  int bh = blockIdx.y; int b = bh >> 4, h = bh & 15;
  int tid = threadIdx.x;
  int d = tid & 63, r8 = (tid >> 6) * 8;
  size_t i0 = ((size_t)(bh*64 + t)*2) * 2048;
  size_t i1 = i0 + 2048;
  int mb = ((bh*64 + t)*2) * 32;
  #pragma unroll
  for (int rr = 0; rr < 8; rr++){
    int r = r8 + rr;
    float m0 = Mp[mb + r],      m1 = Mp[mb + 32 + r];
    float l0 = Lp[mb + r],      l1 = Lp[mb + 32 + r];
    float ms = fmaxf(m0, m1);
    float w0 = __expf(m0 - ms), w1 = __expf(m1 - ms);
    float den = w0*l0 + w1*l1;
    float o = (w0*(float)Opart[i0 + (size_t)r*64 + d] + w1*(float)Opart[i1 + (size_t)r*64 + d]) / den;
    attn_out[(size_t)(b*SEQ + t*32 + r)*EMBED + h*HD + d] = f2bf(o);
  }
}

// ---------------- GEMM2: 64x128 tile (2 blocks/CU), attn_out @ w_out + b_out -> fp32 ----------------

__global__ __launch_bounds__(256) void k_gemm_out(
    const unsigned short* __restrict__ A,    // [4096][1024] bf16
    const unsigned short* __restrict__ BT,   // [1024][1024] bf16
    const float* __restrict__ bias,          // [1024]
    float* __restrict__ out)
{
  __shared__ __align__(16) unsigned short As[64*32];   // 4 KB
  __shared__ __align__(16) unsigned short Bs[128*32];  // 8 KB
  const int K = EMBED;
  int m0 = blockIdx.x * 64, n0 = blockIdx.y * 128;
  int tid = threadIdx.x, lane = tid & 63, wave = tid >> 6;
  int wm = wave >> 1, wn = wave & 1;      // wave -> 32m x 64n subtile
  int l16 = lane & 15, quad = lane >> 4;
  f32x4 acc[2][4] = {};
  int ra = tid >> 2, ca = (tid & 3) * 8;  // A: 256 granules, 1/thread
  int c0i = wave*64 + lane, c1i = 256 + wave*64 + lane;  // B: 512 granules, 2/thread
  int rb0 = c0i >> 2, cb0 = (c0i & 3) * 8;
  int rb1 = c1i >> 2, cb1 = (c1i & 3) * 8;
  unsigned short* lA  = &As[(wave*64)*8];
  unsigned short* lB0 = &Bs[(wave*64)*8];
  unsigned short* lB1 = &Bs[(256 + wave*64)*8];
  for (int k0 = 0; k0 < K; k0 += 32){
    async_ld16((void*)&A [(size_t)(m0 + ra)*K + k0 + ca],   (void*)lA);
    async_ld16((void*)&BT[(size_t)(n0 + rb0)*K + k0 + cb0], (void*)lB0);
    async_ld16((void*)&BT[(size_t)(n0 + rb1)*K + k0 + cb1], (void*)lB1);
    __syncthreads();
    bf16x8 af[2], bfr[4];
    #pragma unroll
    for (int mi = 0; mi < 2; mi++) af[mi]  = *(const bf16x8*)&As[(wm*32 + mi*16 + l16)*32 + quad*8];
    #pragma unroll
    for (int ni = 0; ni < 4; ni++) bfr[ni] = *(const bf16x8*)&Bs[(wn*64 + ni*16 + l16)*32 + quad*8];
    #pragma unroll
    for (int mi = 0; mi < 2; mi++)
      #pragma unroll
      for (int ni = 0; ni < 4; ni++)
        acc[mi][ni] = __builtin_amdgcn_mfma_f32_16x16x32_bf16(af[mi], bfr[ni], acc[mi][ni], 0, 0, 0);
    __syncthreads();
  }
  #pragma unroll
  for (int mi = 0; mi < 2; mi++)
    #pragma unroll
    for (int ni = 0; ni < 4; ni++)
      #pragma unroll
      for (int rr = 0; rr < 4; rr++){
        int row = m0 + wm*32 + mi*16 + quad*4 + rr;
        int col = n0 + wn*64 + ni*16 + l16;
        out[(size_t)row*EMBED + col] = acc[mi][ni][rr] + bias[col];
      }
}

// ---------------- launch ----------------

extern "C" void kernel_launch(void* const* d_in, const int* in_sizes, int n_in,
                              void* d_out, int out_size, void* d_ws, size_t ws_size,
                              hipStream_t stream) {
  const float* x     = (const float*)d_in[0];
  const float* w_qkv = (const float*)d_in[1];
  const float* b_qkv = (const float*)d_in[2];
  const float* w_out = (const float*)d_in[3];
  const float* b_out = (const float*)d_in[4];
  float* out = (float*)d_out;

  char* ws = (char*)d_ws;
  size_t off = 0;
  auto alloc = [&](size_t bytes) -> void* {
    void* p = ws + off; off += (bytes + 255) & ~(size_t)255; return p;
  };
  unsigned short* xb    = (unsigned short*)alloc((size_t)ROWS * EMBED * 2);      // 8 MB
  unsigned short* wqkvT = (unsigned short*)alloc((size_t)3 * EMBED * EMBED * 2); // 6 MB
  unsigned short* woutT = (unsigned short*)alloc((size_t)EMBED * EMBED * 2);     // 2 MB
  unsigned short* qb    = (unsigned short*)alloc((size_t)ROWS * EMBED * 2);
  unsigned short* kb    = (unsigned short*)alloc((size_t)ROWS * EMBED * 2);
  unsigned short* vTb   = (unsigned short*)alloc((size_t)ROWS * EMBED * 2);      // f16 bits [BH][D][SEQ]
  float* kn = (float*)alloc((size_t)BHD * SEQ * 4);
  _Float16* Opart = (_Float16*)alloc((size_t)BHD * 64 * 2 * 32 * 64 * 2);        // 16.8 MB
  float* Mp    = (float*)alloc((size_t)BHD * 64 * 2 * 32 * 4);                   // 0.5 MB
  float* Lp    = (float*)alloc((size_t)BHD * 64 * 2 * 32 * 4);                   // 0.5 MB
  unsigned short* attnb = xb;  // xb dead after GEMM1 — alias

  k_prep<<<dim3(4096 + 3072 + 1024), dim3(256), 0, stream>>>(x, xb, w_qkv, wqkvT, w_out, woutT);
  k_gemm_qkv<<<dim3(ROWS/128, 3*EMBED/128), dim3(256), 0, stream>>>(xb, wqkvT, b_qkv, qb, kb, vTb, kn);
  k_attn<<<dim3(64, BHD), dim3(128), 0, stream>>>(qb, kb, vTb, kn, Opart, Mp, Lp);
  k_combine<<<dim3(64, BHD), dim3(256), 0, stream>>>(Opart, Mp, Lp, attnb);
  k_gemm_out<<<dim3(ROWS/64, EMBED/128), dim3(256), 0, stream>>>(attnb, woutT, b_out, out);
}